// Round 4
// baseline (7376.468 us; speedup 1.0000x reference)
//
#include <hip/hip_runtime.h>
#include <hip/hip_bf16.h>

// ViT-Base fwd on MI355X. Round 4: inputs FP32, OUTPUT FP32 (reference dtypes).
// Weights transposed+cast to bf16 in ws; residual stream fp32; GEMMs = MFMA bf16.

typedef unsigned short u16;
typedef unsigned int u32;
typedef __attribute__((ext_vector_type(8))) short short8;
typedef __attribute__((ext_vector_type(4))) float f32x4;

#define NTOK 197
#define NPAT 196
#define HDIM 768
#define NHEAD 12
#define MLPD 3072
#define NLAYER 12
#define BATCH 32
#define MTOK 6304   // 32*197
#define MPATCH 6272 // 32*196 = 49*128 exactly

__device__ __forceinline__ float b2f(u16 u) { return __uint_as_float(((u32)u) << 16); }
__device__ __forceinline__ float b2f_lo(u32 u) { return __uint_as_float(u << 16); }
__device__ __forceinline__ float b2f_hi(u32 u) { return __uint_as_float(u & 0xffff0000u); }
__device__ __forceinline__ u16 f2b(float f) {
  u32 x = __float_as_uint(f);
  return (u16)((x + 0x7fffu + ((x >> 16) & 1u)) >> 16);
}
__device__ __forceinline__ float gelu_f(float x) {
  return 0.5f * x * (1.0f + erff(x * 0.7071067811865476f));
}
__device__ __forceinline__ void gll16(const u16* g, u16* l) {
  __builtin_amdgcn_global_load_lds((const __attribute__((address_space(1))) void*)g,
                                   (__attribute__((address_space(3))) void*)l, 16, 0, 0);
}

// ---------------- GEMM: C[M,N] = A[M,K](bf16) @ Bt[N,K]^T(bf16), fused epilogues.
// MODE 0: store bf16            MODE 1: +bias, store f32
// MODE 2: +bias, gelu, bf16     MODE 3: +bias, gelu, += f32 residual
// MODE 4: += f32 residual
template <int MODE>
__global__ __launch_bounds__(256) void gemm_bt(const u16* __restrict__ A,
                                               const u16* __restrict__ Bt,
                                               const float* __restrict__ bias,
                                               u16* __restrict__ obf,
                                               float* __restrict__ of32,
                                               int M, int N, int K) {
  __shared__ __align__(16) u16 As[128 * 32];
  __shared__ __align__(16) u16 Bs[128 * 32];
  const int tid = threadIdx.x;
  const int wave = tid >> 6, lane = tid & 63;
  const int m0 = blockIdx.y * 128, n0 = blockIdx.x * 128;
  const int wm = (wave & 1) * 64, wn = (wave >> 1) * 64;
  const int fr = lane & 15, fq = lane >> 4;

  f32x4 acc[4][4];
#pragma unroll
  for (int i = 0; i < 4; ++i)
#pragma unroll
    for (int j = 0; j < 4; ++j) acc[i][j] = (f32x4){0.f, 0.f, 0.f, 0.f};

  const int c0 = tid, c1 = tid + 256;
  const u16* ga0 = A + (size_t)(m0 + (c0 >> 2)) * K + (c0 & 3) * 8;
  const u16* ga1 = A + (size_t)(m0 + (c1 >> 2)) * K + (c1 & 3) * 8;
  const u16* gb0 = Bt + (size_t)(n0 + (c0 >> 2)) * K + (c0 & 3) * 8;
  const u16* gb1 = Bt + (size_t)(n0 + (c1 >> 2)) * K + (c1 & 3) * 8;
  u16* la0 = As + c0 * 8;
  u16* la1 = As + c1 * 8;
  u16* lb0 = Bs + c0 * 8;
  u16* lb1 = Bs + c1 * 8;

  for (int kt = 0; kt < K; kt += 32) {
    gll16(ga0 + kt, la0);
    gll16(ga1 + kt, la1);
    gll16(gb0 + kt, lb0);
    gll16(gb1 + kt, lb1);
    __syncthreads();
    short8 af[4], bff[4];
#pragma unroll
    for (int i = 0; i < 4; ++i) {
      af[i] = *(const short8*)(As + (wm + 16 * i + fr) * 32 + fq * 8);
      bff[i] = *(const short8*)(Bs + (wn + 16 * i + fr) * 32 + fq * 8);
    }
#pragma unroll
    for (int i = 0; i < 4; ++i)
#pragma unroll
      for (int j = 0; j < 4; ++j)
        acc[i][j] = __builtin_amdgcn_mfma_f32_16x16x32_bf16(af[i], bff[j], acc[i][j], 0, 0, 0);
    __syncthreads();
  }

#pragma unroll
  for (int i = 0; i < 4; ++i) {
    const int rb = m0 + wm + 16 * i + fq * 4;
#pragma unroll
    for (int j = 0; j < 4; ++j) {
      const int col = n0 + wn + 16 * j + fr;
      float bv = 0.f;
      if (MODE == 1 || MODE == 2 || MODE == 3) bv = bias[col];
#pragma unroll
      for (int rr = 0; rr < 4; ++rr) {
        const int row = rb + rr;
        if (row >= M) continue;
        const float vv = acc[i][j][rr];
        const size_t idx = (size_t)row * N + col;
        if (MODE == 0)      obf[idx] = f2b(vv);
        else if (MODE == 1) of32[idx] = vv + bv;
        else if (MODE == 2) obf[idx] = f2b(gelu_f(vv + bv));
        else if (MODE == 3) of32[idx] += gelu_f(vv + bv);
        else                of32[idx] += vv;
      }
    }
  }
}

// ---------------- transpose+cast fp32 [R,C] -> bf16 [C,R]; z selects one of 4 mats
__global__ __launch_bounds__(256) void transp4(const float* s0, u16* d0, int R0, int C0,
                                               const float* s1, u16* d1, int R1, int C1,
                                               const float* s2, u16* d2, int R2, int C2,
                                               const float* s3, u16* d3, int R3, int C3) {
  const float* S;
  u16* D;
  int R, C;
  switch (blockIdx.z) {
    case 0: S = s0; D = d0; R = R0; C = C0; break;
    case 1: S = s1; D = d1; R = R1; C = C1; break;
    case 2: S = s2; D = d2; R = R2; C = C2; break;
    default: S = s3; D = d3; R = R3; C = C3; break;
  }
  const int bx = blockIdx.x, by = blockIdx.y;
  if (bx * 32 >= C || by * 32 >= R) return;
  __shared__ float t[32][33];
  const int tx = threadIdx.x & 31, ty = threadIdx.x >> 5;
#pragma unroll
  for (int k = 0; k < 4; ++k)
    t[ty + k * 8][tx] = S[(size_t)(by * 32 + ty + k * 8) * C + bx * 32 + tx];
  __syncthreads();
#pragma unroll
  for (int k = 0; k < 4; ++k)
    D[(size_t)(bx * 32 + ty + k * 8) * R + by * 32 + tx] = f2b(t[tx][ty + k * 8]);
}

// ---------------- patchify + LN(pn1) -> bf16 [6272,768]
__global__ __launch_bounds__(256) void patch_ln(const float* __restrict__ x,
                                                const float* __restrict__ g,
                                                const float* __restrict__ bta,
                                                u16* __restrict__ out) {
  const int r = blockIdx.x;  // b*196 + patch
  const int bb = r / NPAT, pp = r % NPAT;
  const int gh = pp / 14, gw = pp % 14;
  const int tid = threadIdx.x;  // = p1*16 + p2
  const int p1 = tid >> 4, p2 = tid & 15;
  float v[3];
#pragma unroll
  for (int c = 0; c < 3; ++c)
    v[c] = x[(((size_t)bb * 3 + c) * 224 + gh * 16 + p1) * 224 + gw * 16 + p2];
  float s = v[0] + v[1] + v[2];
  float ss = v[0] * v[0] + v[1] * v[1] + v[2] * v[2];
#pragma unroll
  for (int o = 32; o; o >>= 1) { s += __shfl_xor(s, o); ss += __shfl_xor(ss, o); }
  __shared__ float red[8];
  const int wave = tid >> 6, lane = tid & 63;
  if (lane == 0) { red[wave] = s; red[4 + wave] = ss; }
  __syncthreads();
  const float S = red[0] + red[1] + red[2] + red[3];
  const float SS = red[4] + red[5] + red[6] + red[7];
  const float mean = S * (1.f / HDIM);
  const float rstd = rsqrtf(SS * (1.f / HDIM) - mean * mean + 1e-5f);
  u16* o_ = out + (size_t)r * HDIM;
#pragma unroll
  for (int c = 0; c < 3; ++c) {
    const int e = tid * 3 + c;
    o_[e] = f2b((v[c] - mean) * rstd * g[e] + bta[e]);
  }
}

// ---------------- LN over fp32 rows -> bf16
__global__ __launch_bounds__(256) void ln_rows(const float* __restrict__ X,
                                               const float* __restrict__ g,
                                               const float* __restrict__ bta,
                                               u16* __restrict__ Y) {
  const int r = blockIdx.x;
  const int tid = threadIdx.x;
  const float* x = X + (size_t)r * HDIM;
  float v[3];
#pragma unroll
  for (int i = 0; i < 3; ++i) v[i] = x[tid + 256 * i];
  float s = v[0] + v[1] + v[2];
  float ss = v[0] * v[0] + v[1] * v[1] + v[2] * v[2];
#pragma unroll
  for (int o = 32; o; o >>= 1) { s += __shfl_xor(s, o); ss += __shfl_xor(ss, o); }
  __shared__ float red[8];
  const int wave = tid >> 6, lane = tid & 63;
  if (lane == 0) { red[wave] = s; red[4 + wave] = ss; }
  __syncthreads();
  const float S = red[0] + red[1] + red[2] + red[3];
  const float SS = red[4] + red[5] + red[6] + red[7];
  const float mean = S * (1.f / HDIM);
  const float rstd = rsqrtf(SS * (1.f / HDIM) - mean * mean + 1e-5f);
  u16* y = Y + (size_t)r * HDIM;
#pragma unroll
  for (int i = 0; i < 3; ++i) {
    const int e = tid + 256 * i;
    y[e] = f2b((v[i] - mean) * rstd * g[e] + bta[e]);
  }
}

// ---------------- h[b,n,:] = (n==0 ? cls : LN(pemb,pn2)) + pos  (fp32)
__global__ __launch_bounds__(256) void build_h(const float* __restrict__ pemb,
                                               const float* __restrict__ g,
                                               const float* __restrict__ bta,
                                               const float* __restrict__ cls,
                                               const float* __restrict__ pos,
                                               float* __restrict__ h) {
  const int r = blockIdx.x;  // b*197 + n
  const int bb = r / NTOK, n = r % NTOK;
  const int tid = threadIdx.x;
  float* hr = h + (size_t)r * HDIM;
  if (n == 0) {
#pragma unroll
    for (int i = 0; i < 3; ++i) {
      const int e = tid + 256 * i;
      hr[e] = cls[e] + pos[e];
    }
    return;
  }
  const float* xr = pemb + (size_t)(bb * NPAT + n - 1) * HDIM;
  float v[3];
#pragma unroll
  for (int i = 0; i < 3; ++i) v[i] = xr[tid + 256 * i];
  float s = v[0] + v[1] + v[2];
  float ss = v[0] * v[0] + v[1] * v[1] + v[2] * v[2];
#pragma unroll
  for (int o = 32; o; o >>= 1) { s += __shfl_xor(s, o); ss += __shfl_xor(ss, o); }
  __shared__ float red[8];
  const int wave = tid >> 6, lane = tid & 63;
  if (lane == 0) { red[wave] = s; red[4 + wave] = ss; }
  __syncthreads();
  const float S = red[0] + red[1] + red[2] + red[3];
  const float SS = red[4] + red[5] + red[6] + red[7];
  const float mean = S * (1.f / HDIM);
  const float rstd = rsqrtf(SS * (1.f / HDIM) - mean * mean + 1e-5f);
#pragma unroll
  for (int i = 0; i < 3; ++i) {
    const int e = tid + 256 * i;
    hr[e] = (v[i] - mean) * rstd * g[e] + bta[e] + pos[(size_t)n * HDIM + e];
  }
}

// ---------------- attention (scalar round): grid (384, 13), block 256.
// qkv row = b*197+n: [q(768)|k(768)|v(768)]. K staged in LDS with 16B-chunk
// xor-swizzle (chunk' = dc ^ (m&7)) so the 64-lane b128 reads hit all banks.
__global__ __launch_bounds__(256) void attn_kernel(const u16* __restrict__ qkv,
                                                   u16* __restrict__ out) {
  const int bh = blockIdx.x;
  const int bb = bh / NHEAD, hh = bh % NHEAD;
  const int n0 = blockIdx.y * 16;
  const int tid = threadIdx.x;
  const int wave = tid >> 6, lane = tid & 63;

  __shared__ __align__(16) float qs[16][64];
  __shared__ __align__(16) float ps[16][208];
  __shared__ __align__(16) u16 ks[NTOK * 64];

  for (int e = tid; e < 16 * 64; e += 256) {
    const int qi = e >> 6, d = e & 63;
    const int n = n0 + qi;
    qs[qi][d] = (n < NTOK) ? b2f(qkv[(size_t)(bb * NTOK + n) * 2304 + hh * 64 + d]) : 0.f;
  }
  for (int c = tid; c < NTOK * 8; c += 256) {
    const int m = c >> 3, dc = c & 7;
    const uint4 kk = *(const uint4*)(qkv + (size_t)(bb * NTOK + m) * 2304 + 768 + hh * 64 + dc * 8);
    *(uint4*)(ks + m * 64 + ((dc ^ (m & 7)) * 8)) = kk;
  }
  __syncthreads();

#pragma unroll
  for (int qq = 0; qq < 4; ++qq) {
    const int qi = wave + qq * 4;
    float sv[4];
#pragma unroll
    for (int mc = 0; mc < 4; ++mc) {
      const int m = mc * 64 + lane;
      float acc = 0.f;
      if (m < NTOK) {
        const u16* kr = ks + m * 64;
        const int sw = m & 7;
#pragma unroll
        for (int dc = 0; dc < 8; ++dc) {
          const uint4 kk = *(const uint4*)(kr + ((dc ^ sw) * 8));
          const float* qp = &qs[qi][dc * 8];
          acc += qp[0] * b2f_lo(kk.x) + qp[1] * b2f_hi(kk.x) +
                 qp[2] * b2f_lo(kk.y) + qp[3] * b2f_hi(kk.y) +
                 qp[4] * b2f_lo(kk.z) + qp[5] * b2f_hi(kk.z) +
                 qp[6] * b2f_lo(kk.w) + qp[7] * b2f_hi(kk.w);
        }
        acc *= 0.125f;  // 1/sqrt(64)
      } else {
        acc = -1e30f;
      }
      sv[mc] = acc;
    }
    float mx = fmaxf(fmaxf(sv[0], sv[1]), fmaxf(sv[2], sv[3]));
#pragma unroll
    for (int o = 32; o; o >>= 1) mx = fmaxf(mx, __shfl_xor(mx, o));
    float pv[4], sum = 0.f;
#pragma unroll
    for (int mc = 0; mc < 4; ++mc) { pv[mc] = expf(sv[mc] - mx); sum += pv[mc]; }
#pragma unroll
    for (int o = 32; o; o >>= 1) sum += __shfl_xor(sum, o);
    const float inv = 1.f / sum;
#pragma unroll
    for (int mc = 0; mc < 4; ++mc) {
      const int m = mc * 64 + lane;
      if (m < 208) ps[qi][m] = pv[mc] * inv;
    }
  }
  __syncthreads();

  float ov[4] = {0.f, 0.f, 0.f, 0.f};
  const u16* vp = qkv + (size_t)(bb * NTOK) * 2304 + 1536 + hh * 64 + lane;
  for (int m = 0; m < NTOK; ++m) {
    const float vv = b2f(vp[(size_t)m * 2304]);
#pragma unroll
    for (int qq = 0; qq < 4; ++qq) ov[qq] += ps[wave + qq * 4][m] * vv;
  }
#pragma unroll
  for (int qq = 0; qq < 4; ++qq) {
    const int n = n0 + wave + qq * 4;
    if (n < NTOK) out[(size_t)(bb * NTOK + n) * HDIM + hh * 64 + lane] = f2b(ov[qq]);
  }
}

// ---------------- mean pool over tokens -> FP32 [32,768] (d_out is float*)
__global__ __launch_bounds__(256) void pool_kernel(const float* __restrict__ h,
                                                   float* __restrict__ out) {
  const int bb = blockIdx.x;
  const int tid = threadIdx.x;
#pragma unroll
  for (int i = 0; i < 3; ++i) {
    const int c = tid + 256 * i;
    float s = 0.f;
    for (int n = 0; n < NTOK; ++n) s += h[((size_t)bb * NTOK + n) * HDIM + c];
    out[bb * HDIM + c] = s * (1.f / NTOK);
  }
}

extern "C" void kernel_launch(void* const* d_in, const int* in_sizes, int n_in,
                              void* d_out, int out_size, void* d_ws, size_t ws_size,
                              hipStream_t stream) {
  const float* x = (const float*)d_in[0];
  const float* pn1_g = (const float*)d_in[1];
  const float* pn1_b = (const float*)d_in[2];
  const float* pW = (const float*)d_in[3];
  const float* pb = (const float*)d_in[4];
  const float* pn2_g = (const float*)d_in[5];
  const float* pn2_b = (const float*)d_in[6];
  const float* cls = (const float*)d_in[7];
  const float* pos = (const float*)d_in[8];
  const float* ln1_g = (const float*)d_in[9];
  const float* ln1_b = (const float*)d_in[10];
  const float* qkv_W = (const float*)d_in[11];
  const float* out_W = (const float*)d_in[12];
  const float* ln2_g = (const float*)d_in[13];
  const float* ln2_b = (const float*)d_in[14];
  const float* fc1_W = (const float*)d_in[15];
  const float* fc1_b = (const float*)d_in[16];
  const float* fc2_W = (const float*)d_in[17];
  const float* fc2_b = (const float*)d_in[18];

  // workspace layout (bytes), total ~82.7 MB:
  //   h     f32 [6304,768]            @ 0          (19365888)
  //   y     bf16 [6400,768]           @ 19365888   (9830400; LN out / attn out)
  //   S     scratch                   @ 29196288   (39321600)
  //         = qkvb bf16[6304,2304] | u bf16[6400,3072] | pln bf16 + pemb f32
  //   wl    bf16 per-layer W^T        @ 68517888   (14155776)
  char* ws = (char*)d_ws;
  float* h = (float*)(ws);
  u16* y = (u16*)(ws + 19365888);
  u16* qkvb = (u16*)(ws + 29196288);
  u16* u = (u16*)(ws + 29196288);
  u16* pln = (u16*)(ws + 29196288);                 // 6272*768 bf16 (setup only)
  float* pemb = (float*)(ws + 29196288 + 9633792);  // 6272*768 f32 (setup only)
  u16* wl = (u16*)(ws + 68517888);
  u16* wq = wl;                  // [2304,768]
  u16* wo = wq + 2304 * 768;     // [768,768]
  u16* w1 = wo + 768 * 768;      // [3072,768]
  u16* w2 = w1 + 3072 * 768;     // [768,3072]
  u16* pWt = wl;                 // pW^T [768,768] during setup (overwritten later)

  dim3 blk(256);

  // setup: pW^T, patchify+LN1, patch GEMM (+pb, f32), build h (+LN2, cls, pos)
  transp4<<<dim3(24, 24, 1), blk, 0, stream>>>(pW, pWt, 768, 768, pW, pWt, 768, 768,
                                               pW, pWt, 768, 768, pW, pWt, 768, 768);
  patch_ln<<<dim3(MPATCH), blk, 0, stream>>>(x, pn1_g, pn1_b, pln);
  gemm_bt<1><<<dim3(6, 49), blk, 0, stream>>>(pln, pWt, pb, nullptr, pemb, MPATCH, 768, 768);
  build_h<<<dim3(MTOK), blk, 0, stream>>>(pemb, pn2_g, pn2_b, cls, pos, h);

  for (int l = 0; l < NLAYER; ++l) {
    transp4<<<dim3(96, 96, 4), blk, 0, stream>>>(
        qkv_W + (size_t)l * 768 * 2304, wq, 768, 2304,
        out_W + (size_t)l * 768 * 768, wo, 768, 768,
        fc1_W + (size_t)l * 768 * 3072, w1, 768, 3072,
        fc2_W + (size_t)l * 3072 * 768, w2, 3072, 768);
    ln_rows<<<dim3(MTOK), blk, 0, stream>>>(h, ln1_g + l * 768, ln1_b + l * 768, y);
    gemm_bt<0><<<dim3(18, 50), blk, 0, stream>>>(y, wq, nullptr, qkvb, nullptr, MTOK, 2304, 768);
    attn_kernel<<<dim3(384, 13), blk, 0, stream>>>(qkvb, y);
    gemm_bt<4><<<dim3(6, 50), blk, 0, stream>>>(y, wo, nullptr, nullptr, h, MTOK, 768, 768);
    ln_rows<<<dim3(MTOK), blk, 0, stream>>>(h, ln2_g + l * 768, ln2_b + l * 768, y);
    gemm_bt<2><<<dim3(24, 50), blk, 0, stream>>>(y, w1, fc1_b + l * 3072, u, nullptr, MTOK, 3072, 768);
    gemm_bt<3><<<dim3(6, 50), blk, 0, stream>>>(u, w2, fc2_b + l * 768, nullptr, h, MTOK, 768, 3072);
  }

  pool_kernel<<<dim3(BATCH), blk, 0, stream>>>(h, (float*)d_out);
}

// Round 5
// 4341.491 us; speedup vs baseline: 1.6991x; 1.6991x over previous
//
#include <hip/hip_runtime.h>
#include <hip/hip_bf16.h>

// ViT-Base fwd on MI355X. Round 5: MFMA flash-style attention (one block per (b,h)).
// Inputs FP32, output FP32. Weights bf16 in ws; residual fp32; GEMMs = MFMA bf16.

typedef unsigned short u16;
typedef unsigned int u32;
typedef __attribute__((ext_vector_type(8))) short short8;
typedef __attribute__((ext_vector_type(4))) float f32x4;

#define NTOK 197
#define NPAT 196
#define HDIM 768
#define NHEAD 12
#define MLPD 3072
#define NLAYER 12
#define BATCH 32
#define MTOK 6304   // 32*197
#define MPATCH 6272 // 32*196 = 49*128 exactly

__device__ __forceinline__ float b2f(u16 u) { return __uint_as_float(((u32)u) << 16); }
__device__ __forceinline__ u16 f2b(float f) {
  u32 x = __float_as_uint(f);
  return (u16)((x + 0x7fffu + ((x >> 16) & 1u)) >> 16);
}
__device__ __forceinline__ float gelu_f(float x) {
  return 0.5f * x * (1.0f + erff(x * 0.7071067811865476f));
}
__device__ __forceinline__ void gll16(const u16* g, u16* l) {
  __builtin_amdgcn_global_load_lds((const __attribute__((address_space(1))) void*)g,
                                   (__attribute__((address_space(3))) void*)l, 16, 0, 0);
}

// ---------------- GEMM: C[M,N] = A[M,K](bf16) @ Bt[N,K]^T(bf16), fused epilogues.
// MODE 0: store bf16            MODE 1: +bias, store f32
// MODE 2: +bias, gelu, bf16     MODE 3: +bias, gelu, += f32 residual
// MODE 4: += f32 residual
template <int MODE>
__global__ __launch_bounds__(256) void gemm_bt(const u16* __restrict__ A,
                                               const u16* __restrict__ Bt,
                                               const float* __restrict__ bias,
                                               u16* __restrict__ obf,
                                               float* __restrict__ of32,
                                               int M, int N, int K) {
  __shared__ __align__(16) u16 As[128 * 32];
  __shared__ __align__(16) u16 Bs[128 * 32];
  const int tid = threadIdx.x;
  const int wave = tid >> 6, lane = tid & 63;
  const int m0 = blockIdx.y * 128, n0 = blockIdx.x * 128;
  const int wm = (wave & 1) * 64, wn = (wave >> 1) * 64;
  const int fr = lane & 15, fq = lane >> 4;

  f32x4 acc[4][4];
#pragma unroll
  for (int i = 0; i < 4; ++i)
#pragma unroll
    for (int j = 0; j < 4; ++j) acc[i][j] = (f32x4){0.f, 0.f, 0.f, 0.f};

  const int c0 = tid, c1 = tid + 256;
  const u16* ga0 = A + (size_t)(m0 + (c0 >> 2)) * K + (c0 & 3) * 8;
  const u16* ga1 = A + (size_t)(m0 + (c1 >> 2)) * K + (c1 & 3) * 8;
  const u16* gb0 = Bt + (size_t)(n0 + (c0 >> 2)) * K + (c0 & 3) * 8;
  const u16* gb1 = Bt + (size_t)(n0 + (c1 >> 2)) * K + (c1 & 3) * 8;
  u16* la0 = As + c0 * 8;
  u16* la1 = As + c1 * 8;
  u16* lb0 = Bs + c0 * 8;
  u16* lb1 = Bs + c1 * 8;

  for (int kt = 0; kt < K; kt += 32) {
    gll16(ga0 + kt, la0);
    gll16(ga1 + kt, la1);
    gll16(gb0 + kt, lb0);
    gll16(gb1 + kt, lb1);
    __syncthreads();
    short8 af[4], bff[4];
#pragma unroll
    for (int i = 0; i < 4; ++i) {
      af[i] = *(const short8*)(As + (wm + 16 * i + fr) * 32 + fq * 8);
      bff[i] = *(const short8*)(Bs + (wn + 16 * i + fr) * 32 + fq * 8);
    }
#pragma unroll
    for (int i = 0; i < 4; ++i)
#pragma unroll
      for (int j = 0; j < 4; ++j)
        acc[i][j] = __builtin_amdgcn_mfma_f32_16x16x32_bf16(af[i], bff[j], acc[i][j], 0, 0, 0);
    __syncthreads();
  }

#pragma unroll
  for (int i = 0; i < 4; ++i) {
    const int rb = m0 + wm + 16 * i + fq * 4;
#pragma unroll
    for (int j = 0; j < 4; ++j) {
      const int col = n0 + wn + 16 * j + fr;
      float bv = 0.f;
      if (MODE == 1 || MODE == 2 || MODE == 3) bv = bias[col];
#pragma unroll
      for (int rr = 0; rr < 4; ++rr) {
        const int row = rb + rr;
        if (row >= M) continue;
        const float vv = acc[i][j][rr];
        const size_t idx = (size_t)row * N + col;
        if (MODE == 0)      obf[idx] = f2b(vv);
        else if (MODE == 1) of32[idx] = vv + bv;
        else if (MODE == 2) obf[idx] = f2b(gelu_f(vv + bv));
        else if (MODE == 3) of32[idx] += gelu_f(vv + bv);
        else                of32[idx] += vv;
      }
    }
  }
}

// ---------------- transpose+cast fp32 [R,C] -> bf16 [C,R]; z selects one of 4 mats
__global__ __launch_bounds__(256) void transp4(const float* s0, u16* d0, int R0, int C0,
                                               const float* s1, u16* d1, int R1, int C1,
                                               const float* s2, u16* d2, int R2, int C2,
                                               const float* s3, u16* d3, int R3, int C3) {
  const float* S;
  u16* D;
  int R, C;
  switch (blockIdx.z) {
    case 0: S = s0; D = d0; R = R0; C = C0; break;
    case 1: S = s1; D = d1; R = R1; C = C1; break;
    case 2: S = s2; D = d2; R = R2; C = C2; break;
    default: S = s3; D = d3; R = R3; C = C3; break;
  }
  const int bx = blockIdx.x, by = blockIdx.y;
  if (bx * 32 >= C || by * 32 >= R) return;
  __shared__ float t[32][33];
  const int tx = threadIdx.x & 31, ty = threadIdx.x >> 5;
#pragma unroll
  for (int k = 0; k < 4; ++k)
    t[ty + k * 8][tx] = S[(size_t)(by * 32 + ty + k * 8) * C + bx * 32 + tx];
  __syncthreads();
#pragma unroll
  for (int k = 0; k < 4; ++k)
    D[(size_t)(bx * 32 + ty + k * 8) * R + by * 32 + tx] = f2b(t[tx][ty + k * 8]);
}

// ---------------- patchify + LN(pn1) -> bf16 [6272,768]
__global__ __launch_bounds__(256) void patch_ln(const float* __restrict__ x,
                                                const float* __restrict__ g,
                                                const float* __restrict__ bta,
                                                u16* __restrict__ out) {
  const int r = blockIdx.x;  // b*196 + patch
  const int bb = r / NPAT, pp = r % NPAT;
  const int gh = pp / 14, gw = pp % 14;
  const int tid = threadIdx.x;  // = p1*16 + p2
  const int p1 = tid >> 4, p2 = tid & 15;
  float v[3];
#pragma unroll
  for (int c = 0; c < 3; ++c)
    v[c] = x[(((size_t)bb * 3 + c) * 224 + gh * 16 + p1) * 224 + gw * 16 + p2];
  float s = v[0] + v[1] + v[2];
  float ss = v[0] * v[0] + v[1] * v[1] + v[2] * v[2];
#pragma unroll
  for (int o = 32; o; o >>= 1) { s += __shfl_xor(s, o); ss += __shfl_xor(ss, o); }
  __shared__ float red[8];
  const int wave = tid >> 6, lane = tid & 63;
  if (lane == 0) { red[wave] = s; red[4 + wave] = ss; }
  __syncthreads();
  const float S = red[0] + red[1] + red[2] + red[3];
  const float SS = red[4] + red[5] + red[6] + red[7];
  const float mean = S * (1.f / HDIM);
  const float rstd = rsqrtf(SS * (1.f / HDIM) - mean * mean + 1e-5f);
  u16* o_ = out + (size_t)r * HDIM;
#pragma unroll
  for (int c = 0; c < 3; ++c) {
    const int e = tid * 3 + c;
    o_[e] = f2b((v[c] - mean) * rstd * g[e] + bta[e]);
  }
}

// ---------------- LN over fp32 rows -> bf16
__global__ __launch_bounds__(256) void ln_rows(const float* __restrict__ X,
                                               const float* __restrict__ g,
                                               const float* __restrict__ bta,
                                               u16* __restrict__ Y) {
  const int r = blockIdx.x;
  const int tid = threadIdx.x;
  const float* x = X + (size_t)r * HDIM;
  float v[3];
#pragma unroll
  for (int i = 0; i < 3; ++i) v[i] = x[tid + 256 * i];
  float s = v[0] + v[1] + v[2];
  float ss = v[0] * v[0] + v[1] * v[1] + v[2] * v[2];
#pragma unroll
  for (int o = 32; o; o >>= 1) { s += __shfl_xor(s, o); ss += __shfl_xor(ss, o); }
  __shared__ float red[8];
  const int wave = tid >> 6, lane = tid & 63;
  if (lane == 0) { red[wave] = s; red[4 + wave] = ss; }
  __syncthreads();
  const float S = red[0] + red[1] + red[2] + red[3];
  const float SS = red[4] + red[5] + red[6] + red[7];
  const float mean = S * (1.f / HDIM);
  const float rstd = rsqrtf(SS * (1.f / HDIM) - mean * mean + 1e-5f);
  u16* y = Y + (size_t)r * HDIM;
#pragma unroll
  for (int i = 0; i < 3; ++i) {
    const int e = tid + 256 * i;
    y[e] = f2b((v[i] - mean) * rstd * g[e] + bta[e]);
  }
}

// ---------------- h[b,n,:] = (n==0 ? cls : LN(pemb,pn2)) + pos  (fp32)
__global__ __launch_bounds__(256) void build_h(const float* __restrict__ pemb,
                                               const float* __restrict__ g,
                                               const float* __restrict__ bta,
                                               const float* __restrict__ cls,
                                               const float* __restrict__ pos,
                                               float* __restrict__ h) {
  const int r = blockIdx.x;  // b*197 + n
  const int bb = r / NTOK, n = r % NTOK;
  const int tid = threadIdx.x;
  float* hr = h + (size_t)r * HDIM;
  if (n == 0) {
#pragma unroll
    for (int i = 0; i < 3; ++i) {
      const int e = tid + 256 * i;
      hr[e] = cls[e] + pos[e];
    }
    return;
  }
  const float* xr = pemb + (size_t)(bb * NPAT + n - 1) * HDIM;
  float v[3];
#pragma unroll
  for (int i = 0; i < 3; ++i) v[i] = xr[tid + 256 * i];
  float s = v[0] + v[1] + v[2];
  float ss = v[0] * v[0] + v[1] * v[1] + v[2] * v[2];
#pragma unroll
  for (int o = 32; o; o >>= 1) { s += __shfl_xor(s, o); ss += __shfl_xor(ss, o); }
  __shared__ float red[8];
  const int wave = tid >> 6, lane = tid & 63;
  if (lane == 0) { red[wave] = s; red[4 + wave] = ss; }
  __syncthreads();
  const float S = red[0] + red[1] + red[2] + red[3];
  const float SS = red[4] + red[5] + red[6] + red[7];
  const float mean = S * (1.f / HDIM);
  const float rstd = rsqrtf(SS * (1.f / HDIM) - mean * mean + 1e-5f);
#pragma unroll
  for (int i = 0; i < 3; ++i) {
    const int e = tid + 256 * i;
    hr[e] = (v[i] - mean) * rstd * g[e] + bta[e] + pos[(size_t)n * HDIM + e];
  }
}

// ---------------- MFMA attention: one block per (b,h); 4 waves; block 256.
// K in LDS [208][72] (2-way-free banks), V transposed [64][232] (16B-aligned,
// 2-way-free), per-wave P [16][240] bf16. Wave w owns q-tiles w, w+4, w+8, w+12.
// All tail regions (K rows >=197, V cols >=197, P cols >=208) zeroed: MFMA
// 0*NaN would poison accumulators otherwise.
__global__ __launch_bounds__(256) void attn_mfma(const u16* __restrict__ qkv,
                                                 u16* __restrict__ out) {
  const int bh = blockIdx.x;
  const int bb = bh / NHEAD, hh = bh % NHEAD;
  const int tid = threadIdx.x;
  const int wave = tid >> 6, lane = tid & 63;
  const int l15 = lane & 15, quad = lane >> 4;

  __shared__ __align__(16) u16 Ks[208 * 72];
  __shared__ __align__(16) u16 Vt[64 * 232];
  __shared__ __align__(16) u16 Ps[4][16 * 240];

  const u16* base = qkv + (size_t)(bb * NTOK) * 2304 + hh * 64;

  // stage K (rows 0..196) + zero rows 197..207
  for (int c = tid; c < NTOK * 8; c += 256) {
    const int m = c >> 3, dc = c & 7;
    const uint4 kk = *(const uint4*)(base + (size_t)m * 2304 + 768 + dc * 8);
    *(uint4*)(Ks + m * 72 + dc * 8) = kk;
  }
  for (int c = tid; c < 11 * 72; c += 256) Ks[197 * 72 + c] = 0;
  // zero Vt cols 197..231, then stage V transposed (cols 0..196) — disjoint
  for (int c = tid; c < 64 * 35; c += 256) Vt[(c / 35) * 232 + 197 + (c % 35)] = 0;
  for (int c = tid; c < NTOK * 8; c += 256) {
    const int m = c >> 3, dc = c & 7;
    const uint4 kk = *(const uint4*)(base + (size_t)m * 2304 + 1536 + dc * 8);
    const u16* e = (const u16*)&kk;
#pragma unroll
    for (int j = 0; j < 8; ++j) Vt[(dc * 8 + j) * 232 + m] = e[j];
  }
  // zero Ps cols 208..239 (read range ends at 223; 224..239 never read)
  for (int c = tid; c < 4 * 16 * 32; c += 256) {
    const int w = c >> 9, rc = c & 511;
    Ps[w][(rc >> 5) * 240 + 208 + (rc & 31)] = 0;
  }
  __syncthreads();

  for (int t = wave; t < 13; t += 4) {
    const int qrow = t * 16 + l15;
    const int qr = qrow < NTOK ? qrow : NTOK - 1;  // clamp: masked at store
    const u16* qp = qkv + (size_t)(bb * NTOK + qr) * 2304 + hh * 64 + quad * 8;
    const short8 qf0 = *(const short8*)qp;
    const short8 qf1 = *(const short8*)(qp + 32);

    f32x4 s[13];
#pragma unroll
    for (int mt = 0; mt < 13; ++mt) s[mt] = (f32x4){0.f, 0.f, 0.f, 0.f};
#pragma unroll
    for (int mt = 0; mt < 13; ++mt) {
      const u16* kr = Ks + (mt * 16 + l15) * 72 + quad * 8;
      const short8 kf0 = *(const short8*)kr;
      const short8 kf1 = *(const short8*)(kr + 32);
      s[mt] = __builtin_amdgcn_mfma_f32_16x16x32_bf16(qf0, kf0, s[mt], 0, 0, 0);
      s[mt] = __builtin_amdgcn_mfma_f32_16x16x32_bf16(qf1, kf1, s[mt], 0, 0, 0);
    }

    // softmax: row q = t*16 + quad*4 + r lives on the 16 lanes of this quad
    u16* pw = Ps[wave];
    float inv[4];
#pragma unroll
    for (int r = 0; r < 4; ++r) {
      const bool tail_ok = l15 < 5;  // col m = 192+l15 < 197
      float mx = -3.0e38f;
#pragma unroll
      for (int mt = 0; mt < 13; ++mt) {
        const bool ok = (mt < 12) || tail_ok;
        mx = fmaxf(mx, ok ? s[mt][r] * 0.125f : -3.0e38f);
      }
      mx = fmaxf(mx, __shfl_xor(mx, 1));
      mx = fmaxf(mx, __shfl_xor(mx, 2));
      mx = fmaxf(mx, __shfl_xor(mx, 4));
      mx = fmaxf(mx, __shfl_xor(mx, 8));
      float sum = 0.f;
#pragma unroll
      for (int mt = 0; mt < 13; ++mt) {
        const bool ok = (mt < 12) || tail_ok;
        const float p = ok ? __expf(s[mt][r] * 0.125f - mx) : 0.f;
        s[mt][r] = p;
        sum += p;
      }
      sum += __shfl_xor(sum, 1);
      sum += __shfl_xor(sum, 2);
      sum += __shfl_xor(sum, 4);
      sum += __shfl_xor(sum, 8);
      inv[r] = 1.f / sum;
    }
#pragma unroll
    for (int mt = 0; mt < 13; ++mt)
#pragma unroll
      for (int r = 0; r < 4; ++r)
        pw[(quad * 4 + r) * 240 + mt * 16 + l15] = f2b(s[mt][r] * inv[r]);

    // PV: P[16][224] @ Vt -> O[16][64]
    f32x4 o[4];
#pragma unroll
    for (int dt = 0; dt < 4; ++dt) o[dt] = (f32x4){0.f, 0.f, 0.f, 0.f};
#pragma unroll
    for (int ks = 0; ks < 7; ++ks) {
      const short8 af = *(const short8*)(pw + l15 * 240 + ks * 32 + quad * 8);
#pragma unroll
      for (int dt = 0; dt < 4; ++dt) {
        const short8 bf = *(const short8*)(Vt + (dt * 16 + l15) * 232 + ks * 32 + quad * 8);
        o[dt] = __builtin_amdgcn_mfma_f32_16x16x32_bf16(af, bf, o[dt], 0, 0, 0);
      }
    }
#pragma unroll
    for (int dt = 0; dt < 4; ++dt)
#pragma unroll
      for (int r = 0; r < 4; ++r) {
        const int n = t * 16 + quad * 4 + r;
        if (n < NTOK)
          out[(size_t)(bb * NTOK + n) * HDIM + hh * 64 + dt * 16 + l15] = f2b(o[dt][r]);
      }
  }
}

// ---------------- mean pool over tokens -> FP32 [32,768] (d_out is float*)
__global__ __launch_bounds__(256) void pool_kernel(const float* __restrict__ h,
                                                   float* __restrict__ out) {
  const int bb = blockIdx.x;
  const int tid = threadIdx.x;
#pragma unroll
  for (int i = 0; i < 3; ++i) {
    const int c = tid + 256 * i;
    float s = 0.f;
    for (int n = 0; n < NTOK; ++n) s += h[((size_t)bb * NTOK + n) * HDIM + c];
    out[bb * HDIM + c] = s * (1.f / NTOK);
  }
}

extern "C" void kernel_launch(void* const* d_in, const int* in_sizes, int n_in,
                              void* d_out, int out_size, void* d_ws, size_t ws_size,
                              hipStream_t stream) {
  const float* x = (const float*)d_in[0];
  const float* pn1_g = (const float*)d_in[1];
  const float* pn1_b = (const float*)d_in[2];
  const float* pW = (const float*)d_in[3];
  const float* pb = (const float*)d_in[4];
  const float* pn2_g = (const float*)d_in[5];
  const float* pn2_b = (const float*)d_in[6];
  const float* cls = (const float*)d_in[7];
  const float* pos = (const float*)d_in[8];
  const float* ln1_g = (const float*)d_in[9];
  const float* ln1_b = (const float*)d_in[10];
  const float* qkv_W = (const float*)d_in[11];
  const float* out_W = (const float*)d_in[12];
  const float* ln2_g = (const float*)d_in[13];
  const float* ln2_b = (const float*)d_in[14];
  const float* fc1_W = (const float*)d_in[15];
  const float* fc1_b = (const float*)d_in[16];
  const float* fc2_W = (const float*)d_in[17];
  const float* fc2_b = (const float*)d_in[18];

  // workspace layout (bytes), total ~82.7 MB:
  //   h     f32 [6304,768]            @ 0          (19365888)
  //   y     bf16 [6400,768]           @ 19365888   (9830400; LN out / attn out)
  //   S     scratch                   @ 29196288   (39321600)
  //         = qkvb bf16[6304,2304] | u bf16[6400,3072] | pln bf16 + pemb f32
  //   wl    bf16 per-layer W^T        @ 68517888   (14155776)
  char* ws = (char*)d_ws;
  float* h = (float*)(ws);
  u16* y = (u16*)(ws + 19365888);
  u16* qkvb = (u16*)(ws + 29196288);
  u16* u = (u16*)(ws + 29196288);
  u16* pln = (u16*)(ws + 29196288);                 // 6272*768 bf16 (setup only)
  float* pemb = (float*)(ws + 29196288 + 9633792);  // 6272*768 f32 (setup only)
  u16* wl = (u16*)(ws + 68517888);
  u16* wq = wl;                  // [2304,768]
  u16* wo = wq + 2304 * 768;     // [768,768]
  u16* w1 = wo + 768 * 768;      // [3072,768]
  u16* w2 = w1 + 3072 * 768;     // [768,3072]
  u16* pWt = wl;                 // pW^T [768,768] during setup (overwritten later)

  dim3 blk(256);

  // setup: pW^T, patchify+LN1, patch GEMM (+pb, f32), build h (+LN2, cls, pos)
  transp4<<<dim3(24, 24, 1), blk, 0, stream>>>(pW, pWt, 768, 768, pW, pWt, 768, 768,
                                               pW, pWt, 768, 768, pW, pWt, 768, 768);
  patch_ln<<<dim3(MPATCH), blk, 0, stream>>>(x, pn1_g, pn1_b, pln);
  gemm_bt<1><<<dim3(6, 49), blk, 0, stream>>>(pln, pWt, pb, nullptr, pemb, MPATCH, 768, 768);
  build_h<<<dim3(MTOK), blk, 0, stream>>>(pemb, pn2_g, pn2_b, cls, pos, h);

  for (int l = 0; l < NLAYER; ++l) {
    transp4<<<dim3(96, 96, 4), blk, 0, stream>>>(
        qkv_W + (size_t)l * 768 * 2304, wq, 768, 2304,
        out_W + (size_t)l * 768 * 768, wo, 768, 768,
        fc1_W + (size_t)l * 768 * 3072, w1, 768, 3072,
        fc2_W + (size_t)l * 3072 * 768, w2, 3072, 768);
    ln_rows<<<dim3(MTOK), blk, 0, stream>>>(h, ln1_g + l * 768, ln1_b + l * 768, y);
    gemm_bt<0><<<dim3(18, 50), blk, 0, stream>>>(y, wq, nullptr, qkvb, nullptr, MTOK, 2304, 768);
    attn_mfma<<<dim3(384), blk, 0, stream>>>(qkvb, y);
    gemm_bt<4><<<dim3(6, 50), blk, 0, stream>>>(y, wo, nullptr, nullptr, h, MTOK, 768, 768);
    ln_rows<<<dim3(MTOK), blk, 0, stream>>>(h, ln2_g + l * 768, ln2_b + l * 768, y);
    gemm_bt<2><<<dim3(24, 50), blk, 0, stream>>>(y, w1, fc1_b + l * 3072, u, nullptr, MTOK, 3072, 768);
    gemm_bt<3><<<dim3(6, 50), blk, 0, stream>>>(u, w2, fc2_b + l * 768, nullptr, h, MTOK, 768, 3072);
  }

  pool_kernel<<<dim3(BATCH), blk, 0, stream>>>(h, (float*)d_out);
}